// Round 3
// baseline (702.334 us; speedup 1.0000x reference)
//
#include <hip/hip_runtime.h>
#include <hip/hip_bf16.h>

typedef __attribute__((ext_vector_type(8)))  short bf16x8_t;
typedef __attribute__((ext_vector_type(16))) float f32x16_t;
typedef __attribute__((ext_vector_type(4)))  float f32x4_t;

#define HN 10
#define BN 32768
#define DH 256
#define MT 128

#define HE   65536      // elems per (arr,head) weight matrix
#define ARRE 655360     // elems per layer-array (10 heads)

// LDS layout (bytes)
#define OFF_ABUF  0          // 128 x 256 bf16, swizzled       (65536)
#define OFF_WST   65536      // 4 x 16KB weight slices         (65536)
#define OFF_W1S   131072     // W1[h] 1024 f32                 (4096)
#define OFF_B1S   135168     // b1[h] 256 f32                  (1024)
#define OFF_BBIAS 136192     // b2,b32,b31,b41,b42 (5x256) + b51,b52 (4) f32 (5136)
#define OFF_S51   141328     // 2 partials x 128 x 2 f32       (2048)
#define OFF_S52   143376     //                                (2048)
#define SMEM_BYTES 145424

// counted-vmcnt barriers: keep the 2 newest stage-loads (next+1 slice) in flight
#define SLICE_BAR() asm volatile("s_waitcnt vmcnt(2)\ns_barrier" ::: "memory")
#define MID_BAR()   asm volatile("s_waitcnt vmcnt(2) lgkmcnt(0)\ns_barrier" ::: "memory")

__device__ __forceinline__ unsigned swzoff(int row, int colb) {
  // [128][256] bf16 row-major, 512B/row; XOR row bits into byte bits 4-7
  return (unsigned)(row * 512 + (colb ^ ((row & 15) << 4)));
}

__device__ __forceinline__ unsigned short f2bf(float v) {
  __hip_bfloat16 hb = __float2bfloat16(v);
  return *reinterpret_cast<unsigned short*>(&hb);
}

typedef __attribute__((address_space(3))) unsigned lds_u32;
typedef __attribute__((address_space(1))) const unsigned g_u32;
__device__ __forceinline__ void gload16(const void* g, void* l) {
  __builtin_amdgcn_global_load_lds((g_u32*)g, (lds_u32*)l, 16, 0, 0);
}

// ---------------- prep kernels (layout verified R1/R2) ----------------
struct WPtrs { const float* w[5]; };

extern "C" __global__ void pack_big(WPtrs p, unsigned short* __restrict__ dst)
{
  int g = blockIdx.x * blockDim.x + threadIdx.x;  // 409600
  if (g >= 5 * HN * 16 * 8 * 64) return;
  int lane = g & 63; int t = g >> 6;
  int nt = t & 7; t >>= 3;
  int ks = t & 15; t >>= 4;
  int h = t % HN;
  int a = t / HN;
  const float* src = p.w[a] + (size_t)h * 65536
                   + (nt * 32 + (lane & 31)) * 256 + ks * 16 + (lane >> 5) * 8;
  unsigned short* d = dst + (size_t)a * ARRE + (size_t)h * HE
                    + ((ks * 8 + nt) * 64 + lane) * 8;
  #pragma unroll
  for (int j = 0; j < 8; ++j) d[j] = f2bf(src[j]);
}

extern "C" __global__ void pack_w5(const float* __restrict__ w51, const float* __restrict__ w52,
                                   unsigned short* __restrict__ dst)
{
  int g = blockIdx.x * blockDim.x + threadIdx.x;  // 20480
  if (g >= 2 * HN * 16 * 64) return;
  int lane = g & 63; int t = g >> 6;
  int ks = t & 15; t >>= 4;
  int h = t % HN;
  int br = t / HN;
  const float* w = br ? w52 : w51;   // (10,2,256)
  int col = lane & 31;
  int k = ks * 16 + (lane >> 5) * 8;
  unsigned short* d = dst + ((size_t)(br * HN + h) * 16 + ks) * 512 + lane * 8;
  #pragma unroll
  for (int j = 0; j < 8; ++j) {
    float v = (col < 2) ? w[(size_t)h * 512 + col * 256 + k + j] : 0.f;
    d[j] = f2bf(v);
  }
}

// ---------------- fused main kernel ----------------

#define MFMA32 __builtin_amdgcn_mfma_f32_32x32x16_bf16

// One 256x256 GEMM over the 128-row block. Wave tile 64x64 (wm in [0,2), wn in [0,4)).
// 8 slices of 2 K-steps; weights stream through 4 rotating LDS slice-bufs, staged
// depth-2 ahead (slices 2..7 of wcur, then slices 0..1 of wnext).
// MODE 0: relu + in-place write to abuf. MODE 1: relu + save to sv regs (no write).
template<int MODE>
__device__ __forceinline__ void gemm64(char* abuf, char* wst,
                                       const unsigned short* wcur,
                                       const unsigned short* wnext,
                                       const float* biasLDS,
                                       unsigned sv[2][2][8],
                                       int lane, int wm, int wn, int wave)
{
  const int r31 = lane & 31, hi = lane >> 5;
  const float bv0 = biasLDS[wn * 64 + r31];
  const float bv1 = biasLDS[wn * 64 + 32 + r31];
  f32x16_t acc[2][2];
  #pragma unroll
  for (int i = 0; i < 16; ++i) {
    acc[0][0][i] = bv0; acc[0][1][i] = bv1;
    acc[1][0][i] = bv0; acc[1][1][i] = bv1;
  }

  #pragma unroll
  for (int ls = 0; ls < 8; ++ls) {
    // stage slice ls+2 (depth-2 prefetch), 2 insts x 16B x 64 lanes per wave
    const unsigned short* ssrc = nullptr;
    if (ls < 6)      ssrc = wcur + (ls + 2) * 8192;
    else if (wnext)  ssrc = wnext + (ls - 6) * 8192;
    if (ssrc) {
      #pragma unroll
      for (int i = 0; i < 2; ++i)
        gload16(ssrc + i * 4096 + wave * 512 + lane * 8,
                wst + ((ls + 2) & 3) * 16384 + i * 8192 + wave * 1024);
    }
    // compute 2 K-steps from slice buf (ls & 3)
    #pragma unroll
    for (int k2 = 0; k2 < 2; ++k2) {
      const int ks = ls * 2 + k2;
      bf16x8_t a0 = *(const bf16x8_t*)(abuf + swzoff(wm * 64 + r31,      ks * 32 + hi * 16));
      bf16x8_t a1 = *(const bf16x8_t*)(abuf + swzoff(wm * 64 + 32 + r31, ks * 32 + hi * 16));
      const char* wb = wst + (ls & 3) * 16384 + k2 * 8192 + (wn * 2) * 1024 + lane * 16;
      bf16x8_t b0 = *(const bf16x8_t*)(wb);
      bf16x8_t b1 = *(const bf16x8_t*)(wb + 1024);
      acc[0][0] = MFMA32(a0, b0, acc[0][0], 0, 0, 0);
      acc[0][1] = MFMA32(a0, b1, acc[0][1], 0, 0, 0);
      acc[1][0] = MFMA32(a1, b0, acc[1][0], 0, 0, 0);
      acc[1][1] = MFMA32(a1, b1, acc[1][1], 0, 0, 0);
    }
    if (ls < 7) SLICE_BAR();
    else        MID_BAR();   // all A-reads landed -> in-place overwrite safe
  }

  if (MODE == 0) {
    #pragma unroll
    for (int mt = 0; mt < 2; ++mt) {
      #pragma unroll
      for (int nt = 0; nt < 2; ++nt) {
        int colb = (wn * 64 + nt * 32 + r31) * 2;
        #pragma unroll
        for (int r = 0; r < 16; ++r) {
          int row = wm * 64 + mt * 32 + (r & 3) + 8 * (r >> 2) + 4 * hi;
          *(unsigned short*)(abuf + swzoff(row, colb)) =
              f2bf(fmaxf(acc[mt][nt][r], 0.f));
        }
      }
    }
    MID_BAR();   // writes visible before next layer's reads
  } else {
    #pragma unroll
    for (int mt = 0; mt < 2; ++mt)
      #pragma unroll
      for (int nt = 0; nt < 2; ++nt)
        #pragma unroll
        for (int r2 = 0; r2 < 8; ++r2) {
          unsigned lo = f2bf(fmaxf(acc[mt][nt][2 * r2],     0.f));
          unsigned hh = f2bf(fmaxf(acc[mt][nt][2 * r2 + 1], 0.f));
          sv[mt][nt][r2] = lo | (hh << 16);
        }
  }
}

// final 256->2 layer, K split across 8 waves (mt = wave&3, kh = wave>>2)
__device__ __forceinline__ void final64(const char* abuf, float* s5,
                                        const unsigned short* w5,
                                        const float* b5, int lane, int wave)
{
  const int mt = wave & 3, kh = wave >> 2;
  const int r31 = lane & 31, hi = lane >> 5;
  float bv = (kh == 0 && r31 < 2) ? b5[r31] : 0.f;
  f32x16_t acc;
  #pragma unroll
  for (int i = 0; i < 16; ++i) acc[i] = bv;
  #pragma unroll
  for (int j = 0; j < 8; ++j) {
    int ks = kh * 8 + j;
    bf16x8_t a = *(const bf16x8_t*)(abuf + swzoff(mt * 32 + r31, ks * 32 + hi * 16));
    bf16x8_t b = *(const bf16x8_t*)(w5 + (size_t)(ks * 64 + lane) * 8);
    acc = MFMA32(a, b, acc, 0, 0, 0);
  }
  if (r31 < 2) {
    #pragma unroll
    for (int r = 0; r < 16; ++r) {
      int row = mt * 32 + (r & 3) + 8 * (r >> 2) + 4 * hi;
      s5[kh * 256 + row * 2 + r31] = acc[r];
    }
  }
  MID_BAR();
}

extern "C" __global__ __launch_bounds__(512, 2)
void abnet_main(const float* __restrict__ x, const float* __restrict__ wt,
                const float* __restrict__ mean, const float* __restrict__ stdv,
                const float* __restrict__ mlab, const float* __restrict__ slab,
                const float* __restrict__ W1, const float* __restrict__ b1,
                const float* __restrict__ b2, const float* __restrict__ b31,
                const float* __restrict__ b32, const float* __restrict__ b41,
                const float* __restrict__ b42, const float* __restrict__ b51,
                const float* __restrict__ b52,
                const unsigned short* __restrict__ wpk,
                const unsigned short* __restrict__ w5pk,
                float* __restrict__ out)
{
  extern __shared__ char smem[];
  char*  abuf = smem + OFF_ABUF;
  char*  wst  = smem + OFF_WST;
  float* w1s  = (float*)(smem + OFF_W1S);
  float* b1s  = (float*)(smem + OFF_B1S);
  float* sbb  = (float*)(smem + OFF_BBIAS);
  float* s51  = (float*)(smem + OFF_S51);
  float* s52  = (float*)(smem + OFF_S52);

  const int tid  = threadIdx.x;
  const int lane = tid & 63, wave = tid >> 6;
  const int wm = wave >> 2, wn = wave & 3;
  const int bswz = (blockIdx.x & 7) * 32 + (blockIdx.x >> 3);   // XCD swizzle (256 % 8 == 0)
  const int row0 = bswz * MT;

  // ---- per-row CBF scalars (threads 0..127), f32, in registers ----
  float e_bar = 0, e_bdot = 0, e_lf2b = 0, e_g1 = 0, e_g2 = 0, e_ggi = 0;
  float accu0 = 0.f, accu1 = 0.f, a0r = 0.f;
  float sm_m = 0.f, sm_inv = 0.f, ml0 = 0, ml1 = 0, isl0 = 1, isl1 = 1;
  if (tid < MT) {
    f32x4_t xr = *(const f32x4_t*)(x + (size_t)(row0 + tid) * 4);
    float t1  = xr[0] * stdv[0] + mean[0];
    float w1v = xr[1] * stdv[1] + mean[1];
    float t2  = xr[2] * stdv[2] + mean[2];
    float w2v = xr[3] * stdv[3] + mean[3];
    float s1, c1, s2, c2;
    sincosf(t1, &s1, &c1);
    sincosf(t2, &s2, &c2);
    float px = 3.f * c1 + 3.f * c2;                // OBS_X = 0
    float py = 3.f * s1 + 3.f * s2 - 7.f;          // OBS_Y = 7
    float vx = -3.f * s1 * w1v - 3.f * s2 * w2v;
    float vy =  3.f * c1 * w1v + 3.f * c2 * w2v;
    e_bar  = px * px + py * py - 16.f;             // R^2
    e_bdot = 2.f * (px * vx + py * vy);
    e_lf2b = 2.f * vx * vx + 2.f * vy * vy
           + 2.f * px * (-3.f * c1 * w1v * w1v - 3.f * c2 * w2v * w2v)
           + 2.f * py * (-3.f * s1 * w1v * w1v - 3.f * s2 * w2v * w2v);
    e_g1 = 6.f * (px * s1 - py * c1);
    e_g2 = 6.f * (px * s2 - py * c2);
    e_ggi = 1.f / (e_g1 * e_g1 + e_g2 * e_g2);
    float m = wt[0];
    for (int i = 1; i < HN; ++i) m = fmaxf(m, wt[i]);
    float s = 0.f;
    for (int i = 0; i < HN; ++i) s += __expf(wt[i] - m);
    sm_m = m; sm_inv = 1.f / s;
    ml0 = mlab[0]; ml1 = mlab[1];
    isl0 = 1.f / slab[0]; isl1 = 1.f / slab[1];
  }

  // layer-1 mapping: row = tid&127 (wave-uniform W1 reads -> LDS broadcast)
  const int xrow = tid & 127, xq = tid >> 7;
  const f32x4_t xv = *(const f32x4_t*)(x + (size_t)(row0 + xrow) * 4);

  unsigned sv[2][2][8];   // saved x32 (bf16 pairs)

  // prologue: stage W2[h=0] slices 0,1
  #pragma unroll
  for (int s0 = 0; s0 < 2; ++s0)
    #pragma unroll
    for (int i = 0; i < 2; ++i)
      gload16(wpk + s0 * 8192 + i * 4096 + wave * 512 + lane * 8,
              wst + s0 * 16384 + i * 8192 + wave * 1024);

  for (int h = 0; h < HN; ++h) {
    // ---- head-top staging: W1, b1, all biases (full drain barrier) ----
    for (int i = tid; i < 1280; i += 512) {
      if (i < 1024) w1s[i] = W1[(size_t)h * 1024 + i];
      else          b1s[i - 1024] = b1[(size_t)h * 256 + (i - 1024)];
    }
    for (int i = tid; i < 1284; i += 512) {
      float v;
      if (i < 1280) {
        int a = i >> 8;
        const float* bp = (a == 0) ? b2 : (a == 1) ? b32 : (a == 2) ? b31
                        : (a == 3) ? b41 : b42;
        v = bp[(size_t)h * 256 + (i & 255)];
      } else {
        int j = i - 1280;
        v = (j < 2 ? b51 : b52)[(size_t)h * 2 + (j & 1)];
      }
      sbb[i] = v;
    }
    __syncthreads();

    // ---- layer 1 (K=4, VALU) -> abuf ----
    #pragma unroll
    for (int c8 = 0; c8 < 8; ++c8) {
      int cb = xq * 64 + c8 * 8;
      bf16x8_t pkt;
      #pragma unroll
      for (int j = 0; j < 8; ++j) {
        int c = cb + j;
        f32x4_t w = *(const f32x4_t*)(w1s + c * 4);
        float v = b1s[c] + xv[0] * w[0] + xv[1] * w[1] + xv[2] * w[2] + xv[3] * w[3];
        pkt[j] = (short)f2bf(fmaxf(v, 0.f));
      }
      *(bf16x8_t*)(abuf + swzoff(xrow, cb * 2)) = pkt;
    }
    MID_BAR();

    const unsigned short* W2h  = wpk + (size_t)h * HE;
    const unsigned short* W31h = wpk + 1 * ARRE + (size_t)h * HE;
    const unsigned short* W32h = wpk + 2 * ARRE + (size_t)h * HE;
    const unsigned short* W41h = wpk + 3 * ARRE + (size_t)h * HE;
    const unsigned short* W42h = wpk + 4 * ARRE + (size_t)h * HE;
    const unsigned short* W2n  = (h < 9) ? wpk + (size_t)(h + 1) * HE : nullptr;

    gemm64<0>(abuf, wst, W2h,  W32h, sbb + 0 * 256, sv, lane, wm, wn, wave); // x2
    gemm64<1>(abuf, wst, W32h, W31h, sbb + 1 * 256, sv, lane, wm, wn, wave); // x32 -> regs
    gemm64<0>(abuf, wst, W31h, W41h, sbb + 2 * 256, sv, lane, wm, wn, wave); // x31
    gemm64<0>(abuf, wst, W41h, W42h, sbb + 3 * 256, sv, lane, wm, wn, wave); // x41
    final64(abuf, s51, w5pk + (size_t)h * 8192, sbb + 1280, lane, wave);     // x51

    // ---- restore saved x32 into abuf ----
    {
      const int r31 = lane & 31, hi = lane >> 5;
      #pragma unroll
      for (int mt = 0; mt < 2; ++mt)
        #pragma unroll
        for (int nt = 0; nt < 2; ++nt) {
          int colb = (wn * 64 + nt * 32 + r31) * 2;
          #pragma unroll
          for (int r2 = 0; r2 < 8; ++r2) {
            unsigned v = sv[mt][nt][r2];
            int ra = wm * 64 + mt * 32 + ((2 * r2) & 3) + 8 * ((2 * r2) >> 2) + 4 * hi;
            int rb = wm * 64 + mt * 32 + ((2 * r2 + 1) & 3) + 8 * ((2 * r2 + 1) >> 2) + 4 * hi;
            *(unsigned short*)(abuf + swzoff(ra, colb)) = (unsigned short)(v & 0xffffu);
            *(unsigned short*)(abuf + swzoff(rb, colb)) = (unsigned short)(v >> 16);
          }
        }
      MID_BAR();
    }

    gemm64<0>(abuf, wst, W42h, W2n, sbb + 4 * 256, sv, lane, wm, wn, wave);  // x42
    final64(abuf, s52, w5pk + (size_t)(HN + h) * 8192, sbb + 1282, lane, wave); // x52

    // ---- per-head CBF epilogue ----
    if (tid < MT) {
      float u1 = -(s51[tid * 2 + 0] + s51[256 + tid * 2 + 0]);
      float u2 = -(s51[tid * 2 + 1] + s51[256 + tid * 2 + 1]);
      float z0 = s52[tid * 2 + 0] + s52[256 + tid * 2 + 0];
      float z1 = s52[tid * 2 + 1] + s52[256 + tid * 2 + 1];
      float a0c = 4.f / (1.f + __expf(-z0));
      float bi  = 4.f / (1.f + __expf(-z1));
      if (h == 0) a0r = a0c;
      float hv   = e_lf2b + (a0r + bi) * e_bdot + a0r * bi * e_bar;
      float viol = u1 * e_g1 + u2 * e_g2 - hv;
      float lam  = fmaxf(viol, 0.f) * e_ggi;
      float uu1 = u1 - lam * e_g1;
      float uu2 = u2 - lam * e_g2;
      float whv = __expf(wt[h] - sm_m) * sm_inv;
      accu0 += whv * (uu1 - ml0) * isl0;
      accu1 += whv * (uu2 - ml1) * isl1;
    }
  }

  if (tid < MT) {
    float2 o; o.x = accu0; o.y = accu1;
    *(float2*)(out + (size_t)(row0 + tid) * 2) = o;
  }
}

// ---------------- launch ----------------
extern "C" void kernel_launch(void* const* d_in, const int* in_sizes, int n_in,
                              void* d_out, int out_size, void* d_ws, size_t ws_size,
                              hipStream_t stream)
{
  const float* x    = (const float*)d_in[0];
  const float* wt   = (const float*)d_in[2];
  const float* mean = (const float*)d_in[3];
  const float* stdv = (const float*)d_in[4];
  const float* mlab = (const float*)d_in[5];
  const float* slab = (const float*)d_in[6];
  const float* W1   = (const float*)d_in[7];
  const float* b1   = (const float*)d_in[8];
  WPtrs wp;
  wp.w[0] = (const float*)d_in[9];   // W2
  wp.w[1] = (const float*)d_in[11];  // W31
  wp.w[2] = (const float*)d_in[13];  // W32
  wp.w[3] = (const float*)d_in[15];  // W41
  wp.w[4] = (const float*)d_in[17];  // W42
  const float* b2  = (const float*)d_in[10];
  const float* b31 = (const float*)d_in[12];
  const float* b32 = (const float*)d_in[14];
  const float* b41 = (const float*)d_in[16];
  const float* b42 = (const float*)d_in[18];
  const float* W51 = (const float*)d_in[19];
  const float* b51 = (const float*)d_in[20];
  const float* W52 = (const float*)d_in[21];
  const float* b52 = (const float*)d_in[22];

  unsigned short* wpk  = (unsigned short*)d_ws;
  unsigned short* w5pk = (unsigned short*)((char*)d_ws + (size_t)5 * ARRE * 2);

  hipLaunchKernelGGL(pack_big, dim3(1600), dim3(256), 0, stream, wp, wpk);
  hipLaunchKernelGGL(pack_w5,  dim3(80),   dim3(256), 0, stream, W51, W52, w5pk);

  (void)hipFuncSetAttribute(reinterpret_cast<const void*>(abnet_main),
                            hipFuncAttributeMaxDynamicSharedMemorySize, SMEM_BYTES);
  hipLaunchKernelGGL(abnet_main, dim3(BN / MT), dim3(512), SMEM_BYTES, stream,
                     x, wt, mean, stdv, mlab, slab, W1, b1,
                     b2, b31, b32, b41, b42, b51, b52,
                     wpk, w5pk, (float*)d_out);
}

// Round 4
// 320.015 us; speedup vs baseline: 2.1947x; 2.1947x over previous
//
#include <hip/hip_runtime.h>
#include <hip/hip_bf16.h>

typedef __attribute__((ext_vector_type(8)))  short bf16x8_t;
typedef __attribute__((ext_vector_type(16))) float f32x16_t;
typedef __attribute__((ext_vector_type(4)))  float f32x4_t;

#define HN 10
#define BN 32768
#define DH 256
#define MT 128

#define HE   65536      // elems per (arr,head) weight matrix
#define ARRE 655360     // elems per layer-array (10 heads)

// LDS layout (bytes)
#define OFF_ABUF  0          // 128 x 256 bf16, swizzled (65536)
#define OFF_W1S   65536      // W1[h] 1024 f32           (4096)
#define OFF_B1S   69632      // b1[h] 256 f32            (1024)
#define OFF_B2S   70656      // layer-2 bias 256 f32     (1024)
#define OFF_B3S   71680      // layer-3 bias 256 f32     (1024)
#define OFF_B4S   72704      // layer-4 bias 256 f32     (1024)
#define OFF_B5S   73728      // final bias 2 f32         (8)
#define OFF_S5    73736      // align to 73744: partials 2x128x2 f32 (2048)
#define SMEM_BYTES 75792

__device__ __forceinline__ unsigned swzoff(int row, int colb) {
  // [128][256] bf16 row-major, 512B/row; XOR row bits into byte bits 4-7
  return (unsigned)(row * 512 + (colb ^ ((row & 15) << 4)));
}

__device__ __forceinline__ unsigned short f2bf(float v) {
  __hip_bfloat16 hb = __float2bfloat16(v);
  return *reinterpret_cast<unsigned short*>(&hb);
}

// ---------------- prep kernels (layout verified R1-R3) ----------------
struct WPtrs { const float* w[5]; };

extern "C" __global__ void pack_big(WPtrs p, unsigned short* __restrict__ dst)
{
  int g = blockIdx.x * blockDim.x + threadIdx.x;  // 409600
  if (g >= 5 * HN * 16 * 8 * 64) return;
  int lane = g & 63; int t = g >> 6;
  int nt = t & 7; t >>= 3;
  int ks = t & 15; t >>= 4;
  int h = t % HN;
  int a = t / HN;
  const float* src = p.w[a] + (size_t)h * 65536
                   + (nt * 32 + (lane & 31)) * 256 + ks * 16 + (lane >> 5) * 8;
  unsigned short* d = dst + (size_t)a * ARRE + (size_t)h * HE
                    + ((ks * 8 + nt) * 64 + lane) * 8;
  #pragma unroll
  for (int j = 0; j < 8; ++j) d[j] = f2bf(src[j]);
}

extern "C" __global__ void pack_w5(const float* __restrict__ w51, const float* __restrict__ w52,
                                   unsigned short* __restrict__ dst)
{
  int g = blockIdx.x * blockDim.x + threadIdx.x;  // 20480
  if (g >= 2 * HN * 16 * 64) return;
  int lane = g & 63; int t = g >> 6;
  int ks = t & 15; t >>= 4;
  int h = t % HN;
  int br = t / HN;
  const float* w = br ? w52 : w51;   // (10,2,256)
  int col = lane & 31;
  int k = ks * 16 + (lane >> 5) * 8;
  unsigned short* d = dst + ((size_t)(br * HN + h) * 16 + ks) * 512 + lane * 8;
  #pragma unroll
  for (int j = 0; j < 8; ++j) {
    float v = (col < 2) ? w[(size_t)h * 512 + col * 256 + k + j] : 0.f;
    d[j] = f2bf(v);
  }
}

// ---------------- main kernel: one (rowtile, head, branch) per block ----------------

#define MFMA32 __builtin_amdgcn_mfma_f32_32x32x16_bf16

// In-place 128x256 @ 256x256 GEMM + bias + relu. Wave tile 128 rows x 32 cols
// (wn = wave). Weights read per-wave from L2 as packed b-frags, prefetch depth 2.
// No barriers inside the K-loop.
__device__ __forceinline__ void gemm_ip(char* abuf,
                                        const unsigned short* __restrict__ wl,
                                        const float* biasLDS, int lane, int wn)
{
  const int r31 = lane & 31, hi = lane >> 5;
  const float bv = biasLDS[wn * 32 + r31];
  f32x16_t acc[4];
  #pragma unroll
  for (int i = 0; i < 16; ++i) { acc[0][i] = bv; acc[1][i] = bv; acc[2][i] = bv; acc[3][i] = bv; }

  const bf16x8_t* wp = (const bf16x8_t*)wl + wn * 64 + lane;   // frag(ks) = wp[ks*512]
  bf16x8_t b0 = wp[0], b1 = wp[512];
  #pragma unroll
  for (int ks = 0; ks < 16; ++ks) {
    bf16x8_t bn;
    if (ks < 14) bn = wp[(ks + 2) * 512];
    #pragma unroll
    for (int mt = 0; mt < 4; ++mt) {
      bf16x8_t a = *(const bf16x8_t*)(abuf + swzoff(mt * 32 + r31, ks * 32 + hi * 16));
      acc[mt] = MFMA32(a, b0, acc[mt], 0, 0, 0);
    }
    b0 = b1; b1 = bn;
  }
  __syncthreads();   // all A-reads landed in acc -> in-place overwrite safe
  const int colb = (wn * 32 + r31) * 2;
  #pragma unroll
  for (int mt = 0; mt < 4; ++mt) {
    #pragma unroll
    for (int r = 0; r < 16; ++r) {
      int row = mt * 32 + (r & 3) + 8 * (r >> 2) + 4 * hi;
      *(unsigned short*)(abuf + swzoff(row, colb)) = f2bf(fmaxf(acc[mt][r], 0.f));
    }
  }
  __syncthreads();
}

extern "C" __global__ __launch_bounds__(512, 4)
void abnet_main(const float* __restrict__ x,
                const float* __restrict__ W1, const float* __restrict__ b1,
                const float* __restrict__ b2, const float* __restrict__ b31,
                const float* __restrict__ b32, const float* __restrict__ b41,
                const float* __restrict__ b42, const float* __restrict__ b51,
                const float* __restrict__ b52,
                const unsigned short* __restrict__ wpk,
                const unsigned short* __restrict__ w5pk,
                float* __restrict__ ws51, float* __restrict__ ws52)
{
  extern __shared__ char smem[];
  char*  abuf = smem + OFF_ABUF;
  float* w1s  = (float*)(smem + OFF_W1S);
  float* b1s  = (float*)(smem + OFF_B1S);
  float* b2s  = (float*)(smem + OFF_B2S);
  float* b3s  = (float*)(smem + OFF_B3S);
  float* b4s  = (float*)(smem + OFF_B4S);
  float* b5s  = (float*)(smem + OFF_B5S);
  float* s5   = (float*)(smem + OFF_S5 + 8);   // 2x128x2 f32

  const int tid  = threadIdx.x;
  const int lane = tid & 63, wave = tid >> 6;
  const int rt = blockIdx.x & 255;
  const int hb = blockIdx.x >> 8;        // 0..19
  const int h  = hb >> 1, br = hb & 1;
  const int row0 = rt * MT;

  const float* b3 = br ? b32 : b31;
  const float* b4 = br ? b42 : b41;
  const float* b5 = br ? b52 : b51;

  // ---- stage W1, b1 and all biases for this (h, br) ----
  for (int i = tid; i < 1024; i += 512) w1s[i] = W1[(size_t)h * 1024 + i];
  for (int i = tid; i < 256 * 4 + 2; i += 512) {
    if      (i < 256)  b1s[i]       = b1[(size_t)h * 256 + i];
    else if (i < 512)  b2s[i - 256] = b2[(size_t)h * 256 + (i - 256)];
    else if (i < 768)  b3s[i - 512] = b3[(size_t)h * 256 + (i - 512)];
    else if (i < 1024) b4s[i - 768] = b4[(size_t)h * 256 + (i - 768)];
    else               b5s[i - 1024] = b5[(size_t)h * 2 + (i - 1024)];
  }
  __syncthreads();

  // ---- layer 1 (K=4, VALU) -> abuf ----
  {
    const int xrow = tid & 127, xq = tid >> 7;
    const f32x4_t xv = *(const f32x4_t*)(x + (size_t)(row0 + xrow) * 4);
    #pragma unroll
    for (int c8 = 0; c8 < 8; ++c8) {
      int cb = xq * 64 + c8 * 8;
      bf16x8_t pkt;
      #pragma unroll
      for (int j = 0; j < 8; ++j) {
        int c = cb + j;
        f32x4_t w = *(const f32x4_t*)(w1s + c * 4);
        float v = b1s[c] + xv[0] * w[0] + xv[1] * w[1] + xv[2] * w[2] + xv[3] * w[3];
        pkt[j] = (short)f2bf(fmaxf(v, 0.f));
      }
      *(bf16x8_t*)(abuf + swzoff(xrow, cb * 2)) = pkt;
    }
  }
  __syncthreads();

  // ---- three 256x256 layers, in place ----
  gemm_ip(abuf, wpk + (size_t)h * HE,                          b2s, lane, wave); // x2
  gemm_ip(abuf, wpk + (size_t)(1 + br) * ARRE + (size_t)h * HE, b3s, lane, wave); // x3b
  gemm_ip(abuf, wpk + (size_t)(3 + br) * ARRE + (size_t)h * HE, b4s, lane, wave); // x4b

  // ---- final 256->2, K split over wave>>2, M split over wave&3 ----
  {
    const unsigned short* w5 = w5pk + (size_t)(br * HN + h) * 8192;
    const int mt = wave & 3, kh = wave >> 2;
    const int r31 = lane & 31, hi = lane >> 5;
    float bv = (kh == 0 && r31 < 2) ? b5s[r31] : 0.f;
    f32x16_t acc;
    #pragma unroll
    for (int i = 0; i < 16; ++i) acc[i] = bv;
    #pragma unroll
    for (int j = 0; j < 8; ++j) {
      int ks = kh * 8 + j;
      bf16x8_t a = *(const bf16x8_t*)(abuf + swzoff(mt * 32 + r31, ks * 32 + hi * 16));
      bf16x8_t b = *(const bf16x8_t*)(w5 + (size_t)(ks * 64 + lane) * 8);
      acc = MFMA32(a, b, acc, 0, 0, 0);
    }
    if (r31 < 2) {
      #pragma unroll
      for (int r = 0; r < 16; ++r) {
        int row = mt * 32 + (r & 3) + 8 * (r >> 2) + 4 * hi;
        s5[kh * 256 + row * 2 + r31] = acc[r];
      }
    }
  }
  __syncthreads();

  // ---- write raw final outputs (activation applied in epilogue kernel) ----
  if (tid < 256) {
    int row = tid >> 1, c = tid & 1;
    float v = s5[row * 2 + c] + s5[256 + row * 2 + c];
    float* wsout = br ? ws52 : ws51;
    wsout[((size_t)h * BN + row0 + row) * 2 + c] = v;
  }
}

// ---------------- epilogue: CBF + softmax-weighted head combine ----------------
extern "C" __global__ __launch_bounds__(256)
void abnet_epi(const float* __restrict__ x, const float* __restrict__ wt,
               const float* __restrict__ mean, const float* __restrict__ stdv,
               const float* __restrict__ mlab, const float* __restrict__ slab,
               const float* __restrict__ ws51, const float* __restrict__ ws52,
               float* __restrict__ out)
{
  const int row = blockIdx.x * 256 + threadIdx.x;
  f32x4_t xr = *(const f32x4_t*)(x + (size_t)row * 4);
  float t1  = xr[0] * stdv[0] + mean[0];
  float w1v = xr[1] * stdv[1] + mean[1];
  float t2  = xr[2] * stdv[2] + mean[2];
  float w2v = xr[3] * stdv[3] + mean[3];
  float s1, c1, s2, c2;
  sincosf(t1, &s1, &c1);
  sincosf(t2, &s2, &c2);
  float px = 3.f * c1 + 3.f * c2;                // OBS_X = 0
  float py = 3.f * s1 + 3.f * s2 - 7.f;          // OBS_Y = 7
  float vx = -3.f * s1 * w1v - 3.f * s2 * w2v;
  float vy =  3.f * c1 * w1v + 3.f * c2 * w2v;
  float e_bar  = px * px + py * py - 16.f;       // R^2
  float e_bdot = 2.f * (px * vx + py * vy);
  float e_lf2b = 2.f * vx * vx + 2.f * vy * vy
               + 2.f * px * (-3.f * c1 * w1v * w1v - 3.f * c2 * w2v * w2v)
               + 2.f * py * (-3.f * s1 * w1v * w1v - 3.f * s2 * w2v * w2v);
  float e_g1 = 6.f * (px * s1 - py * c1);
  float e_g2 = 6.f * (px * s2 - py * c2);
  float e_ggi = 1.f / (e_g1 * e_g1 + e_g2 * e_g2);

  float m = wt[0];
  for (int i = 1; i < HN; ++i) m = fmaxf(m, wt[i]);
  float s = 0.f;
  for (int i = 0; i < HN; ++i) s += __expf(wt[i] - m);
  float sm_inv = 1.f / s;
  float ml0 = mlab[0], ml1 = mlab[1];
  float isl0 = 1.f / slab[0], isl1 = 1.f / slab[1];

  float a0r = 4.f / (1.f + __expf(-ws52[(size_t)row * 2 + 0]));   // head 0, col 0
  float accu0 = 0.f, accu1 = 0.f;
  for (int h = 0; h < HN; ++h) {
    float u1 = -ws51[((size_t)h * BN + row) * 2 + 0];
    float u2 = -ws51[((size_t)h * BN + row) * 2 + 1];
    float bi = 4.f / (1.f + __expf(-ws52[((size_t)h * BN + row) * 2 + 1]));
    float hv   = e_lf2b + (a0r + bi) * e_bdot + a0r * bi * e_bar;
    float viol = u1 * e_g1 + u2 * e_g2 - hv;
    float lam  = fmaxf(viol, 0.f) * e_ggi;
    float uu1 = u1 - lam * e_g1;
    float uu2 = u2 - lam * e_g2;
    float whv = __expf(wt[h] - m) * sm_inv;
    accu0 += whv * (uu1 - ml0) * isl0;
    accu1 += whv * (uu2 - ml1) * isl1;
  }
  float2 o; o.x = accu0; o.y = accu1;
  *(float2*)(out + (size_t)row * 2) = o;
}

// ---------------- launch ----------------
extern "C" void kernel_launch(void* const* d_in, const int* in_sizes, int n_in,
                              void* d_out, int out_size, void* d_ws, size_t ws_size,
                              hipStream_t stream)
{
  const float* x    = (const float*)d_in[0];
  const float* wt   = (const float*)d_in[2];
  const float* mean = (const float*)d_in[3];
  const float* stdv = (const float*)d_in[4];
  const float* mlab = (const float*)d_in[5];
  const float* slab = (const float*)d_in[6];
  const float* W1   = (const float*)d_in[7];
  const float* b1   = (const float*)d_in[8];
  WPtrs wp;
  wp.w[0] = (const float*)d_in[9];   // W2
  wp.w[1] = (const float*)d_in[11];  // W31
  wp.w[2] = (const float*)d_in[13];  // W32
  wp.w[3] = (const float*)d_in[15];  // W41
  wp.w[4] = (const float*)d_in[17];  // W42
  const float* b2  = (const float*)d_in[10];
  const float* b31 = (const float*)d_in[12];
  const float* b32 = (const float*)d_in[14];
  const float* b41 = (const float*)d_in[16];
  const float* b42 = (const float*)d_in[18];
  const float* W51 = (const float*)d_in[19];
  const float* b51 = (const float*)d_in[20];
  const float* W52 = (const float*)d_in[21];
  const float* b52 = (const float*)d_in[22];

  char* wsb = (char*)d_ws;
  unsigned short* wpk  = (unsigned short*)wsb;                       // 6,553,600 B
  unsigned short* w5pk = (unsigned short*)(wsb + 6553600);           //   327,680 B
  float* ws51 = (float*)(wsb + 6881280);                             // 2,621,440 B
  float* ws52 = (float*)(wsb + 9502720);                             // 2,621,440 B

  hipLaunchKernelGGL(pack_big, dim3(1600), dim3(256), 0, stream, wp, wpk);
  hipLaunchKernelGGL(pack_w5,  dim3(80),   dim3(256), 0, stream, W51, W52, w5pk);

  (void)hipFuncSetAttribute(reinterpret_cast<const void*>(abnet_main),
                            hipFuncAttributeMaxDynamicSharedMemorySize, SMEM_BYTES);
  hipLaunchKernelGGL(abnet_main, dim3(256 * HN * 2), dim3(512), SMEM_BYTES, stream,
                     x, W1, b1, b2, b31, b32, b41, b42, b51, b52,
                     wpk, w5pk, ws51, ws52);
  hipLaunchKernelGGL(abnet_epi, dim3(BN / 256), dim3(256), 0, stream,
                     x, wt, mean, stdv, mlab, slab, ws51, ws52, (float*)d_out);
}